// Round 1
// baseline (1036.846 us; speedup 1.0000x reference)
//
#include <hip/hip_runtime.h>

#define T_LEN 512
#define NB    4096
#define NIN   36
#define NH    16

typedef float f32x4 __attribute__((ext_vector_type(4)));

__device__ __forceinline__ float rcp_fast(float v) { return __builtin_amdgcn_rcpf(v); }
__device__ __forceinline__ float sigm(float a) {
    // 1/(1+2^(-a*log2e)); overflow-safe: a->-inf => rcp(inf)=0, a->+inf => rcp(1)=1
    return rcp_fast(1.0f + exp2f(a * -1.4426950408889634f));
}
__device__ __forceinline__ float tanh_fast(float a) {
    // 1 - 2/(e^{2a}+1); overflow-safe at both ends
    float t = exp2f(a * 2.885390081777927f);
    return 1.0f - 2.0f * rcp_fast(t + 1.0f);
}

// One 64-thread wave per block: 4 batch elements x 16 lanes.
// Lane j owns hidden unit j. Weights live in registers (statically indexed).
// h broadcast via per-group LDS row; x staged via LDS with 2-step global prefetch.
// All LDS sharing is intra-wave -> no __syncthreads needed (per-wave in-order DS).
__global__ __launch_bounds__(64, 1) void gru_fused_kernel(
    const float* __restrict__ x, const float* __restrict__ h0,
    const float* __restrict__ W_ih, const float* __restrict__ W_hh,
    const float* __restrict__ b_ih, const float* __restrict__ b_hh,
    const float* __restrict__ W_s, const float* __restrict__ b_s,
    const float* __restrict__ W_o, const float* __restrict__ b_o,
    float* __restrict__ out_state, float* __restrict__ out_ori)
{
    __shared__ __align__(16) float xbuf[4][NIN];  // 144B/group: 4-bank skew, conflict-free
    __shared__ __align__(16) float hbuf[4][NH];

    const int tid = threadIdx.x;
    const int g   = tid >> 4;
    const int j   = tid & 15;
    const int b   = blockIdx.x * 4 + g;

    // ---- per-lane weights into registers (one-time, L2-resident) ----
    float Wr[NIN], Wz[NIN], Wn[NIN];
    #pragma unroll
    for (int n = 0; n < NIN; ++n) {
        Wr[n] = W_ih[j*NIN + n];
        Wz[n] = W_ih[(NH + j)*NIN + n];
        Wn[n] = W_ih[(2*NH + j)*NIN + n];
    }
    // "extra" projection row per lane: lanes 0-3 -> W_o rows 32..35, lanes 4-6 -> W_s rows 0..2
    const float* exw; float bex;
    if (j < 4)      { exw = W_o + (size_t)(2*NH + j)*NH; bex = b_o[2*NH + j]; }
    else if (j < 7) { exw = W_s + (size_t)(j - 4)*NH;    bex = b_s[j - 4];    }
    else            { exw = W_hh;                        bex = 0.0f;          } // valid dummy, result unstored
    float Ur[NH], Uz[NH], Un[NH], Wo0[NH], Wo1[NH], Wex[NH];
    #pragma unroll
    for (int k = 0; k < NH; ++k) {
        Ur[k]  = W_hh[j*NH + k];
        Uz[k]  = W_hh[(NH + j)*NH + k];
        Un[k]  = W_hh[(2*NH + j)*NH + k];
        Wo0[k] = W_o[j*NH + k];
        Wo1[k] = W_o[(NH + j)*NH + k];
        Wex[k] = exw[k];
    }
    const float br  = b_ih[j]      + b_hh[j];        // r-gate combined bias
    const float bz  = b_ih[NH + j] + b_hh[NH + j];   // z-gate combined bias
    const float bin = b_ih[2*NH + j];                // n-gate input bias (outside r*)
    const float bhn = b_hh[2*NH + j];                // n-gate hidden bias (inside r*)
    const float bo0 = b_o[j], bo1 = b_o[NH + j];

    const float* xb  = x         + (size_t)b * T_LEN * NIN;
    float*       o2  = out_ori   + (size_t)b * T_LEN * NIN;
    float*       o1p = out_state + (size_t)b * T_LEN * 3;

    float h_own = h0[b*NH + j];
    hbuf[g][j] = h_own;

    f32x4 xreg = {0.f, 0.f, 0.f, 0.f};
    if (j < 9) {
        *(f32x4*)&xbuf[g][4*j] = *(const f32x4*)(xb + 4*j);   // x_0 -> LDS
        xreg = *(const f32x4*)(xb + NIN + 4*j);               // x_1 -> regs
    }
    __builtin_amdgcn_wave_barrier();
    asm volatile("s_waitcnt lgkmcnt(0)" ::: "memory");
    __builtin_amdgcn_wave_barrier();

    float xk[NIN];
    #pragma unroll
    for (int i = 0; i < 9; ++i) {
        f32x4 v = *(const f32x4*)&xbuf[g][4*i];
        xk[4*i+0]=v.x; xk[4*i+1]=v.y; xk[4*i+2]=v.z; xk[4*i+3]=v.w;
    }

    #pragma unroll 1
    for (int t = 0; t < T_LEN; ++t) {
        // (A) stage x_{t+1} into LDS (vmcnt wait on xreg auto-inserted; load was ~1 step old)
        if (j < 9) *(f32x4*)&xbuf[g][4*j] = xreg;
        // (B) prefetch x_{t+2} (clamped; redundant tail load is harmless)
        {
            int tn = (t + 2 < T_LEN) ? (t + 2) : (T_LEN - 1);
            if (j < 9) xreg = *(const f32x4*)(xb + (size_t)tn*NIN + 4*j);
        }
        // (C) read h_t (= hs[t-1] for t>0, h0 at t=0); same-address broadcast reads
        __builtin_amdgcn_wave_barrier();
        float hk[NH];
        #pragma unroll
        for (int i = 0; i < 4; ++i) {
            f32x4 v = *(const f32x4*)&hbuf[g][4*i];
            hk[4*i+0]=v.x; hk[4*i+1]=v.y; hk[4*i+2]=v.z; hk[4*i+3]=v.w;
        }
        // (D) output projections of hs[t-1]
        if (t > 0) {
            float o0 = bo0, o1v = bo1, oex = bex;
            #pragma unroll
            for (int k = 0; k < NH; ++k) {
                o0  += Wo0[k]*hk[k];
                o1v += Wo1[k]*hk[k];
                oex += Wex[k]*hk[k];
            }
            size_t ob = (size_t)(t-1) * NIN;
            o2[ob + j]      = o0;
            o2[ob + NH + j] = o1v;
            if (j < 4)      o2[ob + 2*NH + j]          = oex;
            else if (j < 7) o1p[(size_t)(t-1)*3 + (j-4)] = oex;
        }
        // (E) gates: gi from xk (regs, ready), gh from hk; 6 independent FMA chains
        float ar = br, az = bz, an_ = bin;
        #pragma unroll
        for (int n = 0; n < NIN; ++n) {
            ar  += Wr[n]*xk[n];
            az  += Wz[n]*xk[n];
            an_ += Wn[n]*xk[n];
        }
        float hr_ = 0.f, hz_ = 0.f, hn_ = bhn;
        #pragma unroll
        for (int k = 0; k < NH; ++k) {
            hr_ += Ur[k]*hk[k];
            hz_ += Uz[k]*hk[k];
            hn_ += Un[k]*hk[k];
        }
        float r  = sigm(ar + hr_);
        float zg = sigm(az + hz_);
        float nn = tanh_fast(an_ + r * hn_);
        h_own = (1.0f - zg)*nn + zg*h_own;
        // (F) publish hs[t]
        __builtin_amdgcn_wave_barrier();
        hbuf[g][j] = h_own;
        __builtin_amdgcn_wave_barrier();
        // (G) read x_{t+1} from LDS for next iteration (written at (A), in-order DS)
        #pragma unroll
        for (int i = 0; i < 9; ++i) {
            f32x4 v = *(const f32x4*)&xbuf[g][4*i];
            xk[4*i+0]=v.x; xk[4*i+1]=v.y; xk[4*i+2]=v.z; xk[4*i+3]=v.w;
        }
    }

    // epilogue: project hs[T-1]
    __builtin_amdgcn_wave_barrier();
    {
        float hk[NH];
        #pragma unroll
        for (int i = 0; i < 4; ++i) {
            f32x4 v = *(const f32x4*)&hbuf[g][4*i];
            hk[4*i+0]=v.x; hk[4*i+1]=v.y; hk[4*i+2]=v.z; hk[4*i+3]=v.w;
        }
        float o0 = bo0, o1v = bo1, oex = bex;
        #pragma unroll
        for (int k = 0; k < NH; ++k) {
            o0  += Wo0[k]*hk[k];
            o1v += Wo1[k]*hk[k];
            oex += Wex[k]*hk[k];
        }
        size_t ob = (size_t)(T_LEN-1) * NIN;
        o2[ob + j]      = o0;
        o2[ob + NH + j] = o1v;
        if (j < 4)      o2[ob + 2*NH + j]               = oex;
        else if (j < 7) o1p[(size_t)(T_LEN-1)*3 + (j-4)] = oex;
    }
}

extern "C" void kernel_launch(void* const* d_in, const int* in_sizes, int n_in,
                              void* d_out, int out_size, void* d_ws, size_t ws_size,
                              hipStream_t stream) {
    const float* x    = (const float*)d_in[0];
    const float* h0   = (const float*)d_in[1];
    const float* W_ih = (const float*)d_in[2];
    const float* W_hh = (const float*)d_in[3];
    const float* b_ih = (const float*)d_in[4];
    const float* b_hh = (const float*)d_in[5];
    const float* W_s  = (const float*)d_in[6];
    const float* b_s  = (const float*)d_in[7];
    const float* W_o  = (const float*)d_in[8];
    const float* b_o  = (const float*)d_in[9];
    float* out_state = (float*)d_out;
    float* out_ori   = out_state + (size_t)NB * T_LEN * 3;

    gru_fused_kernel<<<dim3(NB/4), dim3(64), 0, stream>>>(
        x, h0, W_ih, W_hh, b_ih, b_hh, W_s, b_s, W_o, b_o, out_state, out_ori);
}

// Round 6
// 754.825 us; speedup vs baseline: 1.3736x; 1.3736x over previous
//
#include <hip/hip_runtime.h>

#define T_LEN 512
#define NB    4096
#define NIN   36
#define NH    16

typedef float f32x4 __attribute__((ext_vector_type(4)));

__device__ __forceinline__ float rcp_fast(float v) { return __builtin_amdgcn_rcpf(v); }
__device__ __forceinline__ float sigm(float a) {
    // 1/(1+2^(-a*log2e)); overflow-safe both directions
    return rcp_fast(1.0f + exp2f(a * -1.4426950408889634f));
}
__device__ __forceinline__ float tanh_fast(float a) {
    float t = exp2f(a * 2.885390081777927f);
    return 1.0f - 2.0f * rcp_fast(t + 1.0f);
}
__device__ __forceinline__ float swz16(float v) {
    // xor-16 within each 32-lane group: offset = (16<<10) | 0x1F
    return __int_as_float(__builtin_amdgcn_ds_swizzle(__float_as_int(v), 0x401F));
}
__device__ __forceinline__ float hadd(f32x4 v) { return (v.x + v.y) + (v.z + v.w); }

// 32 lanes per batch element: lane = 32*gb + 16*half + j.
// half0 owns x-cols 0..19 / h-cols 0..7; half1 owns x-cols 20..35 (+4 zero-pad) / h-cols 8..15.
// Cross-half sums via ds_swizzle xor-16. 2048 blocks -> 2 waves/SIMD. No spills (~200 VGPR).
__global__ __launch_bounds__(64, 2) void gru_fused2(
    const float* __restrict__ x, const float* __restrict__ h0,
    const float* __restrict__ W_ih, const float* __restrict__ W_hh,
    const float* __restrict__ b_ih, const float* __restrict__ b_hh,
    const float* __restrict__ W_s, const float* __restrict__ b_s,
    const float* __restrict__ W_o, const float* __restrict__ b_o,
    float* __restrict__ out_state, float* __restrict__ out_ori)
{
    __shared__ __align__(16) float hbuf[2][NH];

    const int tid  = threadIdx.x;
    const int gb   = tid >> 5;       // batch element within block (0,1)
    const int l    = tid & 31;
    const int half = l >> 4;
    const int j    = l & 15;
    const int b    = blockIdx.x * 2 + gb;

    const int nbase = half ? 20 : 0; // x-column base for this half
    const int kb    = 8 * half;      // h-column base for this half
    const f32x4 z4  = {0.f, 0.f, 0.f, 0.f};

    // ---- gi weights: 5 f32x4 chunks per gate (half1 chunk4 zero-padded) ----
    f32x4 WrV[5], WzV[5], WnV[5];
    #pragma unroll
    for (int i = 0; i < 5; ++i) {
        bool pad = half && (i == 4);
        WrV[i] = pad ? z4 : *(const f32x4*)(W_ih + (0*NH + j)*NIN + nbase + 4*i);
        WzV[i] = pad ? z4 : *(const f32x4*)(W_ih + (1*NH + j)*NIN + nbase + 4*i);
        WnV[i] = pad ? z4 : *(const f32x4*)(W_ih + (2*NH + j)*NIN + nbase + 4*i);
    }
    // ---- gh + projection weights: 2 f32x4 chunks over this half's 8 h-cols ----
    f32x4 UrV[2], UzV[2], UnV[2], WoA[2], WoB[2], WeV[2];
    #pragma unroll
    for (int i = 0; i < 2; ++i) {
        UrV[i] = *(const f32x4*)(W_hh + (0*NH + j)*NH + kb + 4*i);
        UzV[i] = *(const f32x4*)(W_hh + (1*NH + j)*NH + kb + 4*i);
        UnV[i] = *(const f32x4*)(W_hh + (2*NH + j)*NH + kb + 4*i);
        WoA[i] = *(const f32x4*)(W_o + j*NH        + kb + 4*i);
        WoB[i] = *(const f32x4*)(W_o + (NH + j)*NH + kb + 4*i);
    }
    {   // extra projection row: j<4 -> W_o rows 32..35; j=4..6 -> W_s rows 0..2; else zeros
        const float* pe = (j < 4) ? (W_o + (size_t)(2*NH + j)*NH)
                        : (j < 7) ? (W_s + (size_t)(j - 4)*NH) : nullptr;
        #pragma unroll
        for (int i = 0; i < 2; ++i)
            WeV[i] = pe ? *(const f32x4*)(pe + kb + 4*i) : z4;
    }
    // biases: only half0 contributes gate biases to the partial sums (avoid doubling)
    const float br   = half ? 0.f : (b_ih[j]        + b_hh[j]);
    const float bz   = half ? 0.f : (b_ih[NH + j]   + b_hh[NH + j]);
    const float bin  = half ? 0.f : b_ih[2*NH + j];
    const float bhn  = half ? 0.f : b_hh[2*NH + j];
    const float bown = b_o[(half << 4) + j];          // bias of this lane's own output row
    const float bex  = (j < 4) ? b_o[2*NH + j] : (j < 7 ? b_s[j - 4] : 0.f);

    const float* xb  = x         + (size_t)b * T_LEN * NIN;
    float*       o2  = out_ori   + (size_t)b * T_LEN * NIN;
    float*       o1p = out_state + (size_t)b * T_LEN * 3;

    // ---- h state: h_own = h[j] (both halves); hkv = this half's 8 h values ----
    float h_own = h0[b*NH + j];
    f32x4 hkv0  = *(const f32x4*)(h0 + b*NH + kb);
    f32x4 hkv1  = *(const f32x4*)(h0 + b*NH + kb + 4);

    // per-lane x chunk loader (half1's 5th chunk duplicates chunk 3; its weights are zero)
    #define LOADX(TT, XK) do {                                   \
        const float* _p = xb + (size_t)(TT)*NIN + nbase;         \
        (XK)[0] = *(const f32x4*)(_p);                           \
        (XK)[1] = *(const f32x4*)(_p + 4);                       \
        (XK)[2] = *(const f32x4*)(_p + 8);                       \
        (XK)[3] = *(const f32x4*)(_p + 12);                      \
        (XK)[4] = *(const f32x4*)(_p + (half ? 12 : 16));        \
    } while (0)

    #define STEP(TCUR, XK, TNEXT) do {                                        \
        /* gh + projection partials from hkv = h_{t-1} */                     \
        f32x4 aR = UrV[0]*hkv0 + UrV[1]*hkv1;                                 \
        f32x4 aZ = UzV[0]*hkv0 + UzV[1]*hkv1;                                 \
        f32x4 aN = UnV[0]*hkv0 + UnV[1]*hkv1;                                 \
        f32x4 aA = WoA[0]*hkv0 + WoA[1]*hkv1;                                 \
        f32x4 aB = WoB[0]*hkv0 + WoB[1]*hkv1;                                 \
        f32x4 aE = WeV[0]*hkv0 + WeV[1]*hkv1;                                 \
        /* gi partials from this half's x chunk */                            \
        f32x4 gR = WrV[0]*(XK)[0]; f32x4 gZ = WzV[0]*(XK)[0]; f32x4 gN = WnV[0]*(XK)[0]; \
        gR += WrV[1]*(XK)[1]; gZ += WzV[1]*(XK)[1]; gN += WnV[1]*(XK)[1];     \
        gR += WrV[2]*(XK)[2]; gZ += WzV[2]*(XK)[2]; gN += WnV[2]*(XK)[2];     \
        gR += WrV[3]*(XK)[3]; gZ += WzV[3]*(XK)[3]; gN += WnV[3]*(XK)[3];     \
        gR += WrV[4]*(XK)[4]; gZ += WzV[4]*(XK)[4]; gN += WnV[4]*(XK)[4];     \
        /* x consumed: refill this buffer for step TNEXT (in flight ~1.5 steps) */ \
        LOADX(TNEXT, XK);                                                     \
        float sR = hadd(aR) + hadd(gR) + br;                                  \
        float sZ = hadd(aZ) + hadd(gZ) + bz;                                  \
        float sI = hadd(gN) + bin;                                            \
        float sH = hadd(aN) + bhn;                                            \
        float pA = hadd(aA), pB = hadd(aB), pE = hadd(aE);                    \
        /* cross-half reduction (xor-16 within the 32-lane batch group) */    \
        float rs  = sR + swz16(sR);  float zs  = sZ + swz16(sZ);              \
        float is_ = sI + swz16(sI);  float hs_ = sH + swz16(sH);              \
        float oA  = pA + swz16(pA);  float oB  = pB + swz16(pB);              \
        float oE  = pE + swz16(pE);                                           \
        /* gates (duplicated in both halves) */                               \
        float r  = sigm(rs);                                                  \
        float zg = sigm(zs);                                                  \
        float nn = tanh_fast(is_ + r * hs_);                                  \
        h_own = (1.0f - zg)*nn + zg*h_own;                                    \
        /* store outputs of h_{t-1} at row TCUR-1 */                          \
        if ((TCUR) > 0) {                                                     \
            size_t ob = (size_t)((TCUR) - 1) * NIN;                           \
            o2[ob + (half << 4) + j] = (half ? oB : oA) + bown;               \
            if (!half && j < 7) {                                             \
                if (j < 4) o2[ob + 2*NH + j] = oE + bex;                      \
                else       o1p[(size_t)((TCUR) - 1)*3 + (j - 4)] = oE + bex;  \
            }                                                                 \
        }                                                                     \
        /* publish h_t and regather this half's 8 values (intra-wave, in-order DS) */ \
        if (!half) hbuf[gb][j] = h_own;                                       \
        hkv0 = *(const f32x4*)&hbuf[gb][kb];                                  \
        hkv1 = *(const f32x4*)&hbuf[gb][kb + 4];                              \
    } while (0)

    f32x4 xA[5], xB[5];
    LOADX(0, xA);
    LOADX(1, xB);

    #pragma unroll 1
    for (int t = 0; t < T_LEN; t += 2) {
        int tn0 = (t + 2 < T_LEN) ? t + 2 : T_LEN - 1;
        int tn1 = (t + 3 < T_LEN) ? t + 3 : T_LEN - 1;
        STEP(t,     xA, tn0);
        STEP(t + 1, xB, tn1);
    }

    // epilogue: project h_{T-1} (held in hkv) to row T-1
    {
        f32x4 aA = WoA[0]*hkv0 + WoA[1]*hkv1;
        f32x4 aB = WoB[0]*hkv0 + WoB[1]*hkv1;
        f32x4 aE = WeV[0]*hkv0 + WeV[1]*hkv1;
        float pA = hadd(aA), pB = hadd(aB), pE = hadd(aE);
        float oA = pA + swz16(pA);
        float oB = pB + swz16(pB);
        float oE = pE + swz16(pE);
        size_t ob = (size_t)(T_LEN - 1) * NIN;
        o2[ob + (half << 4) + j] = (half ? oB : oA) + bown;
        if (!half && j < 7) {
            if (j < 4) o2[ob + 2*NH + j] = oE + bex;
            else       o1p[(size_t)(T_LEN - 1)*3 + (j - 4)] = oE + bex;
        }
    }
    #undef STEP
    #undef LOADX
}

extern "C" void kernel_launch(void* const* d_in, const int* in_sizes, int n_in,
                              void* d_out, int out_size, void* d_ws, size_t ws_size,
                              hipStream_t stream) {
    const float* x    = (const float*)d_in[0];
    const float* h0   = (const float*)d_in[1];
    const float* W_ih = (const float*)d_in[2];
    const float* W_hh = (const float*)d_in[3];
    const float* b_ih = (const float*)d_in[4];
    const float* b_hh = (const float*)d_in[5];
    const float* W_s  = (const float*)d_in[6];
    const float* b_s  = (const float*)d_in[7];
    const float* W_o  = (const float*)d_in[8];
    const float* b_o  = (const float*)d_in[9];
    float* out_state = (float*)d_out;
    float* out_ori   = out_state + (size_t)NB * T_LEN * 3;

    gru_fused2<<<dim3(NB/2), dim3(64), 0, stream>>>(
        x, h0, W_ih, W_hh, b_ih, b_hh, W_s, b_s, W_o, b_o, out_state, out_ori);
}